// Round 1
// baseline (1238.785 us; speedup 1.0000x reference)
//
#include <hip/hip_runtime.h>
#include <hip/hip_bf16.h>
#include <cstdint>

#define B_ 512
#define S_ 512
#define V_ 5000
#define E_ 100
#define HD_ 64
#define T_ 25
#define START_ 1
#define STOP_ 2

typedef _Float16 half2_t __attribute__((ext_vector_type(2)));

#if __has_builtin(__builtin_amdgcn_fdot2)
__device__ inline float dot2(uint32_t a, uint32_t b, float c) {
  return __builtin_amdgcn_fdot2(__builtin_bit_cast(half2_t, a),
                                __builtin_bit_cast(half2_t, b), c, false);
}
#else
__device__ inline float dot2(uint32_t a, uint32_t b, float c) {
  half2_t ha = __builtin_bit_cast(half2_t, a);
  half2_t hb = __builtin_bit_cast(half2_t, b);
  return c + (float)ha[0] * (float)hb[0] + (float)ha[1] * (float)hb[1];
}
#endif

__device__ inline float sigm(float x) { return 1.0f / (1.0f + __expf(-x)); }
// tanh(x) = 1 - 2/(exp(2x)+1); saturates cleanly to +-1, no NaN at extremes
__device__ inline float tanh_(float x) { return 1.0f - 2.0f / (1.0f + __expf(2.0f * x)); }

// ---------------- K1: P[v][u] = sum_e embed[v][e] * Wih[u][e], per dir --------
__global__ __launch_bounds__(256) void k_proj(const float* __restrict__ embed,
                                              const float* __restrict__ Wf,
                                              const float* __restrict__ Wb,
                                              float* __restrict__ Pf,
                                              float* __restrict__ Pb) {
  __shared__ __align__(16) float embS[16 * E_];
  int v0 = blockIdx.x * 16;
  const float* Wih = blockIdx.y ? Wb : Wf;
  float* P = blockIdx.y ? Pb : Pf;
  int nv = V_ - v0; if (nv > 16) nv = 16;
  for (int idx = threadIdx.x; idx < nv * E_; idx += 256)
    embS[idx] = embed[v0 * E_ + idx];
  __syncthreads();
  int u = threadIdx.x;
  float acc[16];
#pragma unroll
  for (int i = 0; i < 16; i++) acc[i] = 0.f;
  const float4* W4 = (const float4*)(Wih + u * E_);  // 400B row, 16B aligned
  const float4* e4 = (const float4*)embS;
#pragma unroll 5
  for (int q = 0; q < 25; q++) {
    float4 w = W4[q];
#pragma unroll
    for (int vi = 0; vi < 16; vi++) {
      float4 e = e4[vi * 25 + q];
      acc[vi] += w.x * e.x + w.y * e.y + w.z * e.z + w.w * e.w;
    }
  }
  for (int vi = 0; vi < nv; vi++)
    P[(size_t)(v0 + vi) * 256 + u] = acc[vi];
}

// ---------------- K2: BiLSTM recurrence (1 wave = 2 batch elems, 1 dir) ------
__global__ __launch_bounds__(64) void k_lstm(
    const int* __restrict__ sentences,
    const float* __restrict__ Pf, const float* __restrict__ Pb,
    const float* __restrict__ Whh_f, const float* __restrict__ Whh_b,
    const float* __restrict__ bih_f, const float* __restrict__ bhh_f,
    const float* __restrict__ bih_b, const float* __restrict__ bhh_b,
    const float* __restrict__ h0, const float* __restrict__ c0,
    __hip_bfloat16* __restrict__ feat) {
  int j = threadIdx.x;          // 0..63
  int d = blockIdx.y;           // 0 fwd, 1 bwd
  int be0 = blockIdx.x * 2;
  const float* P   = d ? Pb : Pf;
  const float* Whh = d ? Whh_b : Whh_f;
  const float* bih = d ? bih_b : bih_f;
  const float* bhh = d ? bhh_b : bhh_f;

  __shared__ __align__(16) uint32_t W2[32 * 256];  // f16 pair (k=2kp,2kp+1) per u
  __shared__ __align__(16) uint32_t hL[2 * 32];    // f16 h state, [be][32 pairs]
  __shared__ __align__(16) float zbuf[2 * 256];

  // pack Whh (row-major [256u][64k] f32) into f16 pairs: W2[kp*256+u]
  for (int idx = j; idx < 32 * 256; idx += 64) {
    int u = idx & 255, kp = idx >> 8;
    union { _Float16 h[2]; uint32_t u32; } cv;
    cv.h[0] = (_Float16)Whh[u * HD_ + 2 * kp];
    cv.h[1] = (_Float16)Whh[u * HD_ + 2 * kp + 1];
    W2[idx] = cv.u32;
  }
  float4 bias = ((const float4*)bih)[j];
  {
    float4 b2 = ((const float4*)bhh)[j];
    bias.x += b2.x; bias.y += b2.y; bias.z += b2.z; bias.w += b2.w;
  }
  float c_[2];
  _Float16* hLh = (_Float16*)hL;
#pragma unroll
  for (int be = 0; be < 2; be++) {
    float hh = h0[d * (B_ * HD_) + (be0 + be) * HD_ + j];
    c_[be]   = c0[d * (B_ * HD_) + (be0 + be) * HD_ + j];
    hLh[be * 64 + j] = (_Float16)hh;
  }
  __syncthreads();

  const int* sent0 = sentences + (size_t)(be0 + 0) * S_;
  const int* sent1 = sentences + (size_t)(be0 + 1) * S_;
  int tt0 = d ? (S_ - 1) : 0;
  int step = d ? -1 : 1;
  int sA = sent0[tt0], sB = sent1[tt0];
  const float4* P4 = (const float4*)P;
  const uint4* W2q = (const uint4*)W2;
  const uint4* hq  = (const uint4*)hL;

  for (int t = 0; t < S_; t++) {
    int tt = tt0 + step * t;
    int cA = sA, cB = sB;
    if (t + 1 < S_) { int tn = tt + step; sA = sent0[tn]; sB = sent1[tn]; }
    float4 xa = P4[(size_t)cA * 64 + j];   // issued early, consumed post k-loop
    float4 xb = P4[(size_t)cB * 64 + j];

    // stage h (f16 pairs) into registers via uniform b128 reads
    uint32_t ha[32], hb[32];
#pragma unroll
    for (int q = 0; q < 8; q++) {
      uint4 t0 = hq[q];
      ha[4*q+0] = t0.x; ha[4*q+1] = t0.y; ha[4*q+2] = t0.z; ha[4*q+3] = t0.w;
    }
#pragma unroll
    for (int q = 0; q < 8; q++) {
      uint4 t1 = hq[8 + q];
      hb[4*q+0] = t1.x; hb[4*q+1] = t1.y; hb[4*q+2] = t1.z; hb[4*q+3] = t1.w;
    }
    float4 z0 = bias, z1 = bias;
#pragma unroll
    for (int kp = 0; kp < 32; kp++) {
      uint4 w = W2q[kp * 64 + j];          // u = 4j..4j+3
      uint32_t p0 = ha[kp], p1 = hb[kp];
      z0.x = dot2(w.x, p0, z0.x); z0.y = dot2(w.y, p0, z0.y);
      z0.z = dot2(w.z, p0, z0.z); z0.w = dot2(w.w, p0, z0.w);
      z1.x = dot2(w.x, p1, z1.x); z1.y = dot2(w.y, p1, z1.y);
      z1.z = dot2(w.z, p1, z1.z); z1.w = dot2(w.w, p1, z1.w);
    }
    z0.x += xa.x; z0.y += xa.y; z0.z += xa.z; z0.w += xa.w;
    z1.x += xb.x; z1.y += xb.y; z1.z += xb.z; z1.w += xb.w;
    ((float4*)zbuf)[j] = z0;
    ((float4*)zbuf)[64 + j] = z1;
    __syncthreads();
#pragma unroll
    for (int be = 0; be < 2; be++) {
      float iv = zbuf[be * 256 + j];
      float fv = zbuf[be * 256 + 64 + j];
      float gv = zbuf[be * 256 + 128 + j];
      float ov = zbuf[be * 256 + 192 + j];
      float cc = sigm(fv) * c_[be] + sigm(iv) * tanh_(gv);
      c_[be] = cc;
      float hh = sigm(ov) * tanh_(cc);
      hLh[be * 64 + j] = (_Float16)hh;
      feat[((size_t)(be0 + be) * S_ + tt) * 128 + d * 64 + j] = __float2bfloat16(hh);
    }
    __syncthreads();
  }
}

// ---------------- K3: logits[r][j] = feat[r][:] . Wout[j][:] + bout[j] -------
__global__ __launch_bounds__(256) void k_logits(const __hip_bfloat16* __restrict__ feat,
                                                const float* __restrict__ Wout,
                                                const float* __restrict__ bout,
                                                float* __restrict__ logits) {
  __shared__ __align__(16) float featS[8 * 128];
  __shared__ __align__(16) float WoutS[32 * 132];  // padded rows (oversized for j<32 reads)
  __shared__ float boutS[32];
  size_t r0 = (size_t)blockIdx.x * 8;
  for (int idx = threadIdx.x; idx < 8 * 128; idx += 256)
    featS[idx] = __bfloat162float(feat[r0 * 128 + idx]);
  for (int idx = threadIdx.x; idx < 25 * 128; idx += 256)
    WoutS[(idx >> 7) * 132 + (idx & 127)] = Wout[idx];
  if (threadIdx.x < 25) boutS[threadIdx.x] = bout[threadIdx.x];
  __syncthreads();
  int jj = threadIdx.x & 31, rl = threadIdx.x >> 5;
  float acc = (jj < 25) ? boutS[jj] : 0.f;
  const float4* f4 = (const float4*)(featS + rl * 128);
  const float4* w4 = (const float4*)(WoutS + jj * 132);
#pragma unroll 8
  for (int q = 0; q < 32; q++) {
    float4 fv = f4[q];
    float4 wv = w4[q];
    acc += fv.x * wv.x + fv.y * wv.y + fv.z * wv.z + fv.w * wv.w;
  }
  if (jj < 25) logits[(r0 + rl) * 25 + jj] = acc;
}

// ---------------- K4: CRF forward (sequential over t), totals[b] -------------
__global__ __launch_bounds__(64) void k_crf(const float* __restrict__ logits,
                                            const float* __restrict__ trans,
                                            float* __restrict__ totals) {
  __shared__ float prevS[2 * 32], qS[2 * 32], ES[25 * 32], tcol[32];
  int jj = threadIdx.x & 31, g = threadIdx.x >> 5;
  int b = blockIdx.x * 2 + g;
  for (int idx = threadIdx.x; idx < 25 * 32; idx += 64) {
    int i = idx >> 5, j2 = idx & 31;
    ES[idx] = (j2 < 25) ? __expf(trans[i * 25 + j2]) : 0.f;
  }
  if (g == 0) tcol[jj] = (jj < 25) ? trans[jj * 25 + STOP_] : 0.f;
  prevS[g * 32 + jj] = (jj < 25) ? 0.f : -INFINITY;
  __syncthreads();

  float ltn = (jj < 25) ? logits[((size_t)b * S_) * 25 + jj] : 0.f;
  for (int t = 0; t < S_; t++) {
    float lt = ltn;
    if (t + 1 < S_)
      ltn = (jj < 25) ? logits[((size_t)b * S_ + t + 1) * 25 + jj] : 0.f;
    float pj = prevS[g * 32 + jj];
    float m = pj;
#pragma unroll
    for (int off = 16; off > 0; off >>= 1)
      m = fmaxf(m, __shfl_xor(m, off, 32));
    float q = __expf(pj - m);          // j>=25: -inf -> 0
    qS[g * 32 + jj] = q;
    __syncthreads();
    float s = 0.f;
#pragma unroll
    for (int i = 0; i < 25; i++) s += qS[g * 32 + i] * ES[i * 32 + jj];
    float np = lt + m + __logf(s);     // s==0 -> -inf (exact vs fp32 ref underflow)
    __syncthreads();
    prevS[g * 32 + jj] = (jj < 25) ? np : -INFINITY;
  }
  float v = (jj < 25) ? prevS[g * 32 + jj] + tcol[jj] : -INFINITY;
  float m = v;
#pragma unroll
  for (int off = 16; off > 0; off >>= 1)
    m = fmaxf(m, __shfl_xor(m, off, 32));
  float e = __expf(v - m);
#pragma unroll
  for (int off = 16; off > 0; off >>= 1)
    e += __shfl_xor(e, off, 32);
  if (jj == 0) totals[b] = m + __logf(e);
}

// ---------------- K5: gold path score per b ----------------------------------
__global__ __launch_bounds__(256) void k_real(const float* __restrict__ logits,
                                              const int* __restrict__ tags,
                                              const float* __restrict__ trans,
                                              float* __restrict__ reals) {
  __shared__ float red[256];
  int b = blockIdx.x;
  float acc = 0.f;
  for (int s = threadIdx.x; s < S_; s += 256) {
    int tg = tags[(size_t)b * S_ + s];
    int pv = (s == 0) ? START_ : tags[(size_t)b * S_ + s - 1];
    acc += logits[((size_t)b * S_ + s) * 25 + tg] + trans[pv * 25 + tg];
  }
  red[threadIdx.x] = acc;
  __syncthreads();
  for (int off = 128; off > 0; off >>= 1) {
    if (threadIdx.x < off) red[threadIdx.x] += red[threadIdx.x + off];
    __syncthreads();
  }
  if (threadIdx.x == 0)
    reals[b] = red[0] + trans[tags[(size_t)b * S_ + S_ - 1] * 25 + STOP_];
}

// ---------------- K6: out = sum_b totals - reals -----------------------------
__global__ __launch_bounds__(256) void k_final(const float* __restrict__ totals,
                                               const float* __restrict__ reals,
                                               float* __restrict__ out) {
  __shared__ float red[256];
  float acc = 0.f;
  for (int b = threadIdx.x; b < B_; b += 256) acc += totals[b] - reals[b];
  red[threadIdx.x] = acc;
  __syncthreads();
  for (int off = 128; off > 0; off >>= 1) {
    if (threadIdx.x < off) red[threadIdx.x] += red[threadIdx.x + off];
    __syncthreads();
  }
  if (threadIdx.x == 0) out[0] = red[0];
}

// ws layout: Pf 5,120,000 | Pb 5,120,000 | feat(bf16) 67,108,864 |
// logits 26,214,400 | totals 2048 | reals 2048  => ~98.8 MiB total
extern "C" void kernel_launch(void* const* d_in, const int* in_sizes, int n_in,
                              void* d_out, int out_size, void* d_ws, size_t ws_size,
                              hipStream_t stream) {
  const int*   sentences = (const int*)d_in[0];
  const int*   tags  = (const int*)d_in[1];
  const float* embed = (const float*)d_in[2];
  const float* Wih_f = (const float*)d_in[3];
  const float* Whh_f = (const float*)d_in[4];
  const float* bih_f = (const float*)d_in[5];
  const float* bhh_f = (const float*)d_in[6];
  const float* Wih_b = (const float*)d_in[7];
  const float* Whh_b = (const float*)d_in[8];
  const float* bih_b = (const float*)d_in[9];
  const float* bhh_b = (const float*)d_in[10];
  const float* h0    = (const float*)d_in[11];
  const float* c0    = (const float*)d_in[12];
  const float* Wout  = (const float*)d_in[13];
  const float* bout  = (const float*)d_in[14];
  const float* trans = (const float*)d_in[15];

  char* ws = (char*)d_ws;
  float* Pf = (float*)(ws);
  float* Pb = (float*)(ws + 5120000);
  __hip_bfloat16* feat = (__hip_bfloat16*)(ws + 10240000);
  float* logits = (float*)(ws + 10240000 + 67108864);
  float* totals = (float*)(ws + 10240000 + 67108864 + 26214400);
  float* reals  = totals + 512;
  float* out    = (float*)d_out;

  k_proj<<<dim3(313, 2), 256, 0, stream>>>(embed, Wih_f, Wih_b, Pf, Pb);
  k_lstm<<<dim3(256, 2), 64, 0, stream>>>(sentences, Pf, Pb, Whh_f, Whh_b,
                                          bih_f, bhh_f, bih_b, bhh_b, h0, c0, feat);
  k_logits<<<32768, 256, 0, stream>>>(feat, Wout, bout, logits);
  k_crf<<<256, 64, 0, stream>>>(logits, trans, totals);
  k_real<<<512, 256, 0, stream>>>(logits, tags, trans, reals);
  k_final<<<1, 256, 0, stream>>>(totals, reals, out);
}

// Round 2
// 759.660 us; speedup vs baseline: 1.6307x; 1.6307x over previous
//
#include <hip/hip_runtime.h>
#include <hip/hip_bf16.h>
#include <cstdint>

#define B_ 512
#define S_ 512
#define V_ 5000
#define E_ 100
#define HD_ 64
#define T_ 25
#define START_ 1
#define STOP_ 2

typedef _Float16 half2_t __attribute__((ext_vector_type(2)));
typedef __attribute__((ext_vector_type(8))) short short8;
typedef __attribute__((ext_vector_type(4))) float f32x4;

#if __has_builtin(__builtin_amdgcn_fdot2)
__device__ inline float dot2(uint32_t a, uint32_t b, float c) {
  return __builtin_amdgcn_fdot2(__builtin_bit_cast(half2_t, a),
                                __builtin_bit_cast(half2_t, b), c, false);
}
#else
__device__ inline float dot2(uint32_t a, uint32_t b, float c) {
  half2_t ha = __builtin_bit_cast(half2_t, a);
  half2_t hb = __builtin_bit_cast(half2_t, b);
  return c + (float)ha[0] * (float)hb[0] + (float)ha[1] * (float)hb[1];
}
#endif

__device__ inline float sigm(float x) { return 1.0f / (1.0f + __expf(-x)); }
__device__ inline float tanh_(float x) { return 1.0f - 2.0f / (1.0f + __expf(2.0f * x)); }

// ---------------- K1: P[v][packed] = embed[v] . Wih[u], per dir ---------------
// packed layout: u = half*128 + g2*64 + j  ->  idx = half*128 + j*2 + g2
// so k_lstm lane j of half h loads float2 = (x_{u0}, x_{u1}), u0=h*128+j, u1=u0+64
__global__ __launch_bounds__(256) void k_proj(const float* __restrict__ embed,
                                              const float* __restrict__ Wf,
                                              const float* __restrict__ Wb,
                                              float* __restrict__ Pf,
                                              float* __restrict__ Pb) {
  __shared__ __align__(16) float embS[16 * E_];
  int v0 = blockIdx.x * 16;
  const float* Wih = blockIdx.y ? Wb : Wf;
  float* P = blockIdx.y ? Pb : Pf;
  int nv = V_ - v0; if (nv > 16) nv = 16;
  for (int idx = threadIdx.x; idx < nv * E_; idx += 256)
    embS[idx] = embed[v0 * E_ + idx];
  __syncthreads();
  int u = threadIdx.x;
  float acc[16];
#pragma unroll
  for (int i = 0; i < 16; i++) acc[i] = 0.f;
  const float4* W4 = (const float4*)(Wih + u * E_);
  const float4* e4 = (const float4*)embS;
#pragma unroll 5
  for (int q = 0; q < 25; q++) {
    float4 w = W4[q];
#pragma unroll
    for (int vi = 0; vi < 16; vi++) {
      float4 e = e4[vi * 25 + q];
      acc[vi] += w.x * e.x + w.y * e.y + w.z * e.z + w.w * e.w;
    }
  }
  int pk = (u >> 7) * 128 + (u & 63) * 2 + ((u >> 6) & 1);
  for (int vi = 0; vi < nv; vi++)
    P[(size_t)(v0 + vi) * 256 + pk] = acc[vi];
}

// ---------------- K1b: WoutPad[32][128] bf16 (rows >= 25 zero) ----------------
__global__ __launch_bounds__(256) void k_prep(const float* __restrict__ Wout,
                                              __hip_bfloat16* __restrict__ WoutP) {
  int idx = blockIdx.x * 256 + threadIdx.x;
  if (idx < 32 * 128) {
    int r = idx >> 7, c = idx & 127;
    float v = (r < T_) ? Wout[r * 128 + c] : 0.f;
    WoutP[idx] = __float2bfloat16(v);
  }
}

// ---------------- K2: BiLSTM recurrence -----------------------------------
// block = 256 thr = 4 waves; block handles 2 sequences (seq = (be, dir)).
// wave w: sloc = w>>1 (which seq), half = w&1 (units half*128 .. half*128+127).
// Whh rows for lane j (u0 = half*128+j, u1 = u0+64) live in VGPRs as f16 pairs.
// half==0 wave owns gates i,f and the c/h update; half==1 computes g,o and
// ships them through LDS.
__global__ __launch_bounds__(256) void k_lstm(
    const int* __restrict__ sentences,
    const float* __restrict__ Pf, const float* __restrict__ Pb,
    const float* __restrict__ Whh_f, const float* __restrict__ Whh_b,
    const float* __restrict__ bih_f, const float* __restrict__ bhh_f,
    const float* __restrict__ bih_b, const float* __restrict__ bhh_b,
    const float* __restrict__ h0, const float* __restrict__ c0,
    __hip_bfloat16* __restrict__ feat) {
  int tid = threadIdx.x;
  int j = tid & 63;
  int w = tid >> 6;
  int sloc = w >> 1;
  int half = w & 1;
  int seq = blockIdx.x * 2 + sloc;     // 0..1023
  int be = seq & (B_ - 1);
  int d = seq >> 9;                    // 0 fwd, 1 bwd
  const float* P   = d ? Pb : Pf;
  const float* Whh = d ? Whh_b : Whh_f;
  const float* bih = d ? bih_b : bih_f;
  const float* bhh = d ? bhh_b : bhh_f;

  __shared__ __align__(16) uint32_t hS[2][32];  // [sloc][kp] packed f16 pairs
  __shared__ __align__(16) float2 zS[2][64];    // [sloc][j] = (z_g, z_o)

  int u0 = half * 128 + j;
  int u1 = u0 + 64;
  uint32_t w0p[32], w1p[32];
  {
    const float4* r0 = (const float4*)(Whh + u0 * HD_);
    const float4* r1 = (const float4*)(Whh + u1 * HD_);
#pragma unroll
    for (int q = 0; q < 16; q++) {
      float4 a = r0[q], b = r1[q];
      union { _Float16 h[2]; uint32_t u; } c0u, c1u, c2u, c3u;
      c0u.h[0] = (_Float16)a.x; c0u.h[1] = (_Float16)a.y;
      c1u.h[0] = (_Float16)a.z; c1u.h[1] = (_Float16)a.w;
      c2u.h[0] = (_Float16)b.x; c2u.h[1] = (_Float16)b.y;
      c3u.h[0] = (_Float16)b.z; c3u.h[1] = (_Float16)b.w;
      w0p[2 * q] = c0u.u; w0p[2 * q + 1] = c1u.u;
      w1p[2 * q] = c2u.u; w1p[2 * q + 1] = c3u.u;
    }
  }
  float b0 = bih[u0] + bhh[u0];
  float b1 = bih[u1] + bhh[u1];
  float c = 0.f;
  if (half == 0) {
    float hv = h0[(d * B_ + be) * HD_ + j];
    c = c0[(d * B_ + be) * HD_ + j];
    ((_Float16*)hS[sloc])[j] = (_Float16)hv;
  }
  __syncthreads();

  const int* sent = sentences + (size_t)be * S_;
  int tt0 = d ? (S_ - 1) : 0;
  int stp = d ? -1 : 1;
  int tok = sent[tt0];
  int tok1 = sent[tt0 + stp];
  float2 x = *(const float2*)(P + (size_t)tok * 256 + half * 128 + 2 * j);
  const uint4* hS4 = (const uint4*)hS[sloc];

  for (int t = 0; t < S_; t++) {
    int tt = tt0 + stp * t;
    // prefetch x(t+1) and token(t+2)
    float2 xn = x;
    if (t + 1 < S_)
      xn = *(const float2*)(P + (size_t)tok1 * 256 + half * 128 + 2 * j);
    int tok2 = tok1;
    if (t + 2 < S_) tok2 = sent[tt + 2 * stp];

    float accA[2] = {0.f, 0.f}, accB[2] = {0.f, 0.f};
#pragma unroll
    for (int q = 0; q < 8; q++) {
      uint4 hv = hS4[q];
      int kp = 4 * q, a = q & 1;
      accA[a] = dot2(w0p[kp + 0], hv.x, accA[a]);
      accA[a] = dot2(w0p[kp + 1], hv.y, accA[a]);
      accA[a] = dot2(w0p[kp + 2], hv.z, accA[a]);
      accA[a] = dot2(w0p[kp + 3], hv.w, accA[a]);
      accB[a] = dot2(w1p[kp + 0], hv.x, accB[a]);
      accB[a] = dot2(w1p[kp + 1], hv.y, accB[a]);
      accB[a] = dot2(w1p[kp + 2], hv.z, accB[a]);
      accB[a] = dot2(w1p[kp + 3], hv.w, accB[a]);
    }
    float z0 = accA[0] + accA[1] + b0 + x.x;   // half0: i ; half1: g
    float z1 = accB[0] + accB[1] + b1 + x.y;   // half0: f ; half1: o
    if (half) zS[sloc][j] = make_float2(z0, z1);
    __syncthreads();
    if (!half) {
      float2 go = zS[sloc][j];
      float iv = sigm(z0), fv = sigm(z1);
      float gv = tanh_(go.x), ov = sigm(go.y);
      c = fv * c + iv * gv;
      float hh = ov * tanh_(c);
      ((_Float16*)hS[sloc])[j] = (_Float16)hh;
      feat[((size_t)be * S_ + tt) * 128 + d * 64 + j] = __float2bfloat16(hh);
    }
    __syncthreads();
    x = xn;
    tok1 = tok2;
  }
}

// ---------------- K3: logits = feat . WoutP^T + bout via MFMA -----------------
// wave: one 16-row M-tile, two 16-col N-tiles (cols 25..31 padded zero).
// A frag: lane holds feat[r0 + (l&15)][kb*32 + (l>>4)*8 .. +8)
// B frag: lane holds WoutP[nt*16 + (l&15)][kb*32 + (l>>4)*8 .. +8)
// D: col = l&15, row = (l>>4)*4 + reg (m89/m91-verified layout)
__global__ __launch_bounds__(256) void k_logits(const __hip_bfloat16* __restrict__ feat,
                                                const __hip_bfloat16* __restrict__ WoutP,
                                                const float* __restrict__ bout,
                                                float* __restrict__ logits) {
  int w = threadIdx.x >> 6, l = threadIdx.x & 63;
  size_t r0 = ((size_t)blockIdx.x * 4 + w) * 16;
  int mrow = l & 15, kg = l >> 4;
  short8 bfr[2][4];
#pragma unroll
  for (int nt = 0; nt < 2; nt++) {
    int n = nt * 16 + mrow;
#pragma unroll
    for (int kb = 0; kb < 4; kb++)
      bfr[nt][kb] = *(const short8*)(WoutP + n * 128 + kb * 32 + kg * 8);
  }
  f32x4 acc[2];
#pragma unroll
  for (int nt = 0; nt < 2; nt++) {
    int col = nt * 16 + mrow;
    float bb = (col < T_) ? bout[col] : 0.f;
    acc[nt] = (f32x4){bb, bb, bb, bb};
  }
#pragma unroll
  for (int kb = 0; kb < 4; kb++) {
    short8 a = *(const short8*)(feat + (r0 + mrow) * 128 + kb * 32 + kg * 8);
    acc[0] = __builtin_amdgcn_mfma_f32_16x16x32_bf16(a, bfr[0][kb], acc[0], 0, 0, 0);
    acc[1] = __builtin_amdgcn_mfma_f32_16x16x32_bf16(a, bfr[1][kb], acc[1], 0, 0, 0);
  }
#pragma unroll
  for (int nt = 0; nt < 2; nt++) {
    int col = nt * 16 + mrow;
    if (col < T_) {
#pragma unroll
      for (int q = 0; q < 4; q++) {
        int row = kg * 4 + q;
        logits[(r0 + row) * T_ + col] = acc[nt][q];
      }
    }
  }
}

// ---------------- K4: CRF forward, register-resident, shfl broadcast ----------
__global__ __launch_bounds__(64) void k_crf(const float* __restrict__ logits,
                                            const float* __restrict__ trans,
                                            float* __restrict__ totals) {
  int jj = threadIdx.x & 31;
  int g = threadIdx.x >> 5;
  int b = blockIdx.x * 2 + g;
  bool act = jj < T_;
  float Ecol[T_];
#pragma unroll
  for (int i = 0; i < T_; i++)
    Ecol[i] = act ? __expf(trans[i * T_ + jj]) : 0.f;
  float tstop = act ? trans[jj * T_ + STOP_] : -INFINITY;
  float prev = act ? 0.f : -INFINITY;
  const float* lg = logits + (size_t)b * S_ * T_;
  float ltn = act ? lg[jj] : 0.f;
  for (int t = 0; t < S_; t++) {
    float lt = ltn;
    if (t + 1 < S_) ltn = act ? lg[(size_t)(t + 1) * T_ + jj] : 0.f;
    float m = prev;
#pragma unroll
    for (int off = 16; off > 0; off >>= 1)
      m = fmaxf(m, __shfl_xor(m, off, 32));
    float q = __expf(prev - m);
    float s0 = 0.f, s1 = 0.f, s2 = 0.f, s3 = 0.f;
#pragma unroll
    for (int i = 0; i < T_; i += 4) {
      s0 += __shfl(q, i, 32) * Ecol[i];
      if (i + 1 < T_) s1 += __shfl(q, i + 1, 32) * Ecol[i + 1];
      if (i + 2 < T_) s2 += __shfl(q, i + 2, 32) * Ecol[i + 2];
      if (i + 3 < T_) s3 += __shfl(q, i + 3, 32) * Ecol[i + 3];
    }
    float s = (s0 + s1) + (s2 + s3);
    prev = lt + m + __logf(s);     // s==0 -> -inf, matches fp32 underflow
    if (!act) prev = -INFINITY;
  }
  float v = prev + tstop;
  float m = v;
#pragma unroll
  for (int off = 16; off > 0; off >>= 1)
    m = fmaxf(m, __shfl_xor(m, off, 32));
  float e = __expf(v - m);
#pragma unroll
  for (int off = 16; off > 0; off >>= 1)
    e += __shfl_xor(e, off, 32);
  if (jj == 0) totals[b] = m + __logf(e);
}

// ---------------- K5: gold path score per b ----------------------------------
__global__ __launch_bounds__(256) void k_real(const float* __restrict__ logits,
                                              const int* __restrict__ tags,
                                              const float* __restrict__ trans,
                                              float* __restrict__ reals) {
  __shared__ float red[256];
  int b = blockIdx.x;
  float acc = 0.f;
  for (int s = threadIdx.x; s < S_; s += 256) {
    int tg = tags[(size_t)b * S_ + s];
    int pv = (s == 0) ? START_ : tags[(size_t)b * S_ + s - 1];
    acc += logits[((size_t)b * S_ + s) * T_ + tg] + trans[pv * T_ + tg];
  }
  red[threadIdx.x] = acc;
  __syncthreads();
  for (int off = 128; off > 0; off >>= 1) {
    if (threadIdx.x < off) red[threadIdx.x] += red[threadIdx.x + off];
    __syncthreads();
  }
  if (threadIdx.x == 0)
    reals[b] = red[0] + trans[tags[(size_t)b * S_ + S_ - 1] * T_ + STOP_];
}

// ---------------- K6: out = sum_b totals - reals -----------------------------
__global__ __launch_bounds__(256) void k_final(const float* __restrict__ totals,
                                               const float* __restrict__ reals,
                                               float* __restrict__ out) {
  __shared__ float red[256];
  float acc = 0.f;
  for (int b = threadIdx.x; b < B_; b += 256) acc += totals[b] - reals[b];
  red[threadIdx.x] = acc;
  __syncthreads();
  for (int off = 128; off > 0; off >>= 1) {
    if (threadIdx.x < off) red[threadIdx.x] += red[threadIdx.x + off];
    __syncthreads();
  }
  if (threadIdx.x == 0) out[0] = red[0];
}

// ws: Pf 5,120,000 | Pb 5,120,000 | feat(bf16) 67,108,864 | logits 26,214,400
//   | WoutP 8,192 | totals 2,048 | reals 2,048
extern "C" void kernel_launch(void* const* d_in, const int* in_sizes, int n_in,
                              void* d_out, int out_size, void* d_ws, size_t ws_size,
                              hipStream_t stream) {
  const int*   sentences = (const int*)d_in[0];
  const int*   tags  = (const int*)d_in[1];
  const float* embed = (const float*)d_in[2];
  const float* Wih_f = (const float*)d_in[3];
  const float* Whh_f = (const float*)d_in[4];
  const float* bih_f = (const float*)d_in[5];
  const float* bhh_f = (const float*)d_in[6];
  const float* Wih_b = (const float*)d_in[7];
  const float* Whh_b = (const float*)d_in[8];
  const float* bih_b = (const float*)d_in[9];
  const float* bhh_b = (const float*)d_in[10];
  const float* h0    = (const float*)d_in[11];
  const float* c0    = (const float*)d_in[12];
  const float* Wout  = (const float*)d_in[13];
  const float* bout  = (const float*)d_in[14];
  const float* trans = (const float*)d_in[15];

  char* ws = (char*)d_ws;
  float* Pf = (float*)(ws);
  float* Pb = (float*)(ws + 5120000);
  __hip_bfloat16* feat = (__hip_bfloat16*)(ws + 10240000);
  float* logits = (float*)(ws + 10240000 + 67108864);
  __hip_bfloat16* WoutP = (__hip_bfloat16*)(ws + 10240000 + 67108864 + 26214400);
  float* totals = (float*)(ws + 10240000 + 67108864 + 26214400 + 8192);
  float* reals  = totals + B_;
  float* out    = (float*)d_out;

  k_proj<<<dim3(313, 2), 256, 0, stream>>>(embed, Wih_f, Wih_b, Pf, Pb);
  k_prep<<<16, 256, 0, stream>>>(Wout, WoutP);
  k_lstm<<<512, 256, 0, stream>>>(sentences, Pf, Pb, Whh_f, Whh_b,
                                  bih_f, bhh_f, bih_b, bhh_b, h0, c0, feat);
  k_logits<<<4096, 256, 0, stream>>>(feat, WoutP, bout, logits);
  k_crf<<<256, 64, 0, stream>>>(logits, trans, totals);
  k_real<<<512, 256, 0, stream>>>(logits, tags, trans, reals);
  k_final<<<1, 256, 0, stream>>>(totals, reals, out);
}

// Round 3
// 546.082 us; speedup vs baseline: 2.2685x; 1.3911x over previous
//
#include <hip/hip_runtime.h>
#include <hip/hip_bf16.h>
#include <cstdint>

#define B_ 512
#define S_ 512
#define V_ 5000
#define E_ 100
#define HD_ 64
#define T_ 25
#define START_ 1
#define STOP_ 2

typedef _Float16 half2_t __attribute__((ext_vector_type(2)));
typedef __attribute__((ext_vector_type(8))) short short8;
typedef __attribute__((ext_vector_type(4))) float f32x4;

#if __has_builtin(__builtin_amdgcn_fdot2)
__device__ inline float dot2(uint32_t a, uint32_t b, float c) {
  return __builtin_amdgcn_fdot2(__builtin_bit_cast(half2_t, a),
                                __builtin_bit_cast(half2_t, b), c, false);
}
#else
__device__ inline float dot2(uint32_t a, uint32_t b, float c) {
  half2_t ha = __builtin_bit_cast(half2_t, a);
  half2_t hb = __builtin_bit_cast(half2_t, b);
  return c + (float)ha[0] * (float)hb[0] + (float)ha[1] * (float)hb[1];
}
#endif

__device__ inline float sigm(float x) { return 1.0f / (1.0f + __expf(-x)); }
__device__ inline float tanh_(float x) { return 1.0f - 2.0f / (1.0f + __expf(2.0f * x)); }

// ---------------- K1: P[v][j*4+g] = embed[v] . Wih[g*64+j], per dir ----------
// lane j of k_lstm loads float4 = (x_i, x_f, x_g, x_o) for hidden j, coalesced.
__global__ __launch_bounds__(256) void k_proj(const float* __restrict__ embed,
                                              const float* __restrict__ Wf,
                                              const float* __restrict__ Wb,
                                              float* __restrict__ Pf,
                                              float* __restrict__ Pb) {
  __shared__ __align__(16) float embS[16 * E_];
  int v0 = blockIdx.x * 16;
  const float* Wih = blockIdx.y ? Wb : Wf;
  float* P = blockIdx.y ? Pb : Pf;
  int nv = V_ - v0; if (nv > 16) nv = 16;
  for (int idx = threadIdx.x; idx < nv * E_; idx += 256)
    embS[idx] = embed[v0 * E_ + idx];
  __syncthreads();
  int u = threadIdx.x;
  float acc[16];
#pragma unroll
  for (int i = 0; i < 16; i++) acc[i] = 0.f;
  const float4* W4 = (const float4*)(Wih + u * E_);
  const float4* e4 = (const float4*)embS;
#pragma unroll 5
  for (int q = 0; q < 25; q++) {
    float4 w = W4[q];
#pragma unroll
    for (int vi = 0; vi < 16; vi++) {
      float4 e = e4[vi * 25 + q];
      acc[vi] += w.x * e.x + w.y * e.y + w.z * e.z + w.w * e.w;
    }
  }
  int pk = (u & 63) * 4 + (u >> 6);   // hidden j -> float4 slot, gate -> comp
  for (int vi = 0; vi < nv; vi++)
    P[(size_t)(v0 + vi) * 256 + pk] = acc[vi];
}

// ---------------- K1b: WoutPad[32][128] bf16 (rows >= 25 zero) ----------------
__global__ __launch_bounds__(256) void k_prep(const float* __restrict__ Wout,
                                              __hip_bfloat16* __restrict__ WoutP) {
  int idx = blockIdx.x * 256 + threadIdx.x;
  if (idx < 32 * 128) {
    int r = idx >> 7, c = idx & 127;
    float v = (r < T_) ? Wout[r * 128 + c] : 0.f;
    WoutP[idx] = __float2bfloat16(v);
  }
}

// ---------------- K2: BiLSTM recurrence: 1 wave = 1 sequence, no barriers ----
// lane j owns hidden unit j: all 4 gate rows of Whh in VGPRs (f16 pairs).
// h broadcast via wave-synchronous LDS (write b16 + 8 uniform b128 reads).
__global__ __launch_bounds__(64, 1) void k_lstm(
    const int* __restrict__ sentences,
    const float* __restrict__ Pf, const float* __restrict__ Pb,
    const float* __restrict__ Whh_f, const float* __restrict__ Whh_b,
    const float* __restrict__ bih_f, const float* __restrict__ bhh_f,
    const float* __restrict__ bih_b, const float* __restrict__ bhh_b,
    const float* __restrict__ h0, const float* __restrict__ c0,
    __hip_bfloat16* __restrict__ feat) {
  int j = threadIdx.x;                 // 0..63 = hidden unit
  int seq = blockIdx.x;                // 0..1023
  int be = seq & (B_ - 1);
  int d = seq >> 9;                    // 0 fwd, 1 bwd
  const float* P   = d ? Pb : Pf;
  const float* Whh = d ? Whh_b : Whh_f;
  const float* bih = d ? bih_b : bih_f;
  const float* bhh = d ? bhh_b : bhh_f;

  __shared__ __align__(16) uint32_t hS[32];   // 64 f16 h values

  // Whh rows u = g*64 + j, packed to f16 pairs: wp[g][kp] = (W[u][2kp],W[u][2kp+1])
  uint32_t wp[4][32];
  float bg[4];
#pragma unroll
  for (int g = 0; g < 4; g++) {
    int u = g * 64 + j;
    const float4* rp = (const float4*)(Whh + (size_t)u * HD_);
#pragma unroll
    for (int q = 0; q < 16; q++) {
      float4 a = rp[q];
      union { _Float16 h[2]; uint32_t u32; } p0, p1;
      p0.h[0] = (_Float16)a.x; p0.h[1] = (_Float16)a.y;
      p1.h[0] = (_Float16)a.z; p1.h[1] = (_Float16)a.w;
      wp[g][2 * q] = p0.u32; wp[g][2 * q + 1] = p1.u32;
    }
    bg[g] = bih[u] + bhh[u];
  }
  float c = c0[(d * B_ + be) * HD_ + j];
  ((_Float16*)hS)[j] = (_Float16)h0[(d * B_ + be) * HD_ + j];
  asm volatile("s_waitcnt lgkmcnt(0)" ::: "memory");

  const int* sent = sentences + (size_t)be * S_;
  int tt0 = d ? (S_ - 1) : 0;
  int stp = d ? -1 : 1;
  int tok1 = sent[tt0];
  const float4* P4 = (const float4*)P;
  float4 x = P4[(size_t)tok1 * 64 + j];
  tok1 = (S_ > 1) ? sent[tt0 + stp] : tok1;
  const uint4* hS4 = (const uint4*)hS;

  for (int t = 0; t < S_; t++) {
    int tt = tt0 + stp * t;
    float4 xn = x;
    if (t + 1 < S_) xn = P4[(size_t)tok1 * 64 + j];
    int tok2 = tok1;
    if (t + 2 < S_) tok2 = sent[tt + 2 * stp];

    float a0 = 0.f, a1 = 0.f, a2 = 0.f, a3 = 0.f;  // even-kp accs
    float b0 = 0.f, b1 = 0.f, b2 = 0.f, b3 = 0.f;  // odd-kp accs
#pragma unroll
    for (int q = 0; q < 8; q++) {
      uint4 hv = hS4[q];
      int kp = 4 * q;
      a0 = dot2(wp[0][kp], hv.x, a0); b0 = dot2(wp[0][kp + 1], hv.y, b0);
      a0 = dot2(wp[0][kp + 2], hv.z, a0); b0 = dot2(wp[0][kp + 3], hv.w, b0);
      a1 = dot2(wp[1][kp], hv.x, a1); b1 = dot2(wp[1][kp + 1], hv.y, b1);
      a1 = dot2(wp[1][kp + 2], hv.z, a1); b1 = dot2(wp[1][kp + 3], hv.w, b1);
      a2 = dot2(wp[2][kp], hv.x, a2); b2 = dot2(wp[2][kp + 1], hv.y, b2);
      a2 = dot2(wp[2][kp + 2], hv.z, a2); b2 = dot2(wp[2][kp + 3], hv.w, b2);
      a3 = dot2(wp[3][kp], hv.x, a3); b3 = dot2(wp[3][kp + 1], hv.y, b3);
      a3 = dot2(wp[3][kp + 2], hv.z, a3); b3 = dot2(wp[3][kp + 3], hv.w, b3);
    }
    float zi = a0 + b0 + bg[0] + x.x;
    float zf = a1 + b1 + bg[1] + x.y;
    float zg = a2 + b2 + bg[2] + x.z;
    float zo = a3 + b3 + bg[3] + x.w;
    c = sigm(zf) * c + sigm(zi) * tanh_(zg);
    float hh = sigm(zo) * tanh_(c);
    feat[((size_t)be * S_ + tt) * 128 + d * 64 + j] = __float2bfloat16(hh);
    ((_Float16*)hS)[j] = (_Float16)hh;
    asm volatile("s_waitcnt lgkmcnt(0)" ::: "memory");
    x = xn;
    tok1 = tok2;
  }
}

// ---------------- K3: logits = feat . WoutP^T + bout via MFMA -----------------
__global__ __launch_bounds__(256) void k_logits(const __hip_bfloat16* __restrict__ feat,
                                                const __hip_bfloat16* __restrict__ WoutP,
                                                const float* __restrict__ bout,
                                                float* __restrict__ logits) {
  int w = threadIdx.x >> 6, l = threadIdx.x & 63;
  size_t r0 = ((size_t)blockIdx.x * 4 + w) * 16;
  int mrow = l & 15, kg = l >> 4;
  short8 bfr[2][4];
#pragma unroll
  for (int nt = 0; nt < 2; nt++) {
    int n = nt * 16 + mrow;
#pragma unroll
    for (int kb = 0; kb < 4; kb++)
      bfr[nt][kb] = *(const short8*)(WoutP + n * 128 + kb * 32 + kg * 8);
  }
  f32x4 acc[2];
#pragma unroll
  for (int nt = 0; nt < 2; nt++) {
    int col = nt * 16 + mrow;
    float bb = (col < T_) ? bout[col] : 0.f;
    acc[nt] = (f32x4){bb, bb, bb, bb};
  }
#pragma unroll
  for (int kb = 0; kb < 4; kb++) {
    short8 a = *(const short8*)(feat + (r0 + mrow) * 128 + kb * 32 + kg * 8);
    acc[0] = __builtin_amdgcn_mfma_f32_16x16x32_bf16(a, bfr[0][kb], acc[0], 0, 0, 0);
    acc[1] = __builtin_amdgcn_mfma_f32_16x16x32_bf16(a, bfr[1][kb], acc[1], 0, 0, 0);
  }
#pragma unroll
  for (int nt = 0; nt < 2; nt++) {
    int col = nt * 16 + mrow;
    if (col < T_) {
#pragma unroll
      for (int q = 0; q < 4; q++) {
        int row = kg * 4 + q;
        logits[(r0 + row) * T_ + col] = acc[nt][q];
      }
    }
  }
}

// ---------------- K4: CRF forward, 1 wave = 1 batch elem ---------------------
// m via readfirstlane (prev spread across tags is O(10), exp headroom 80+);
// q broadcast via LDS write + uniform b128 reads (no bpermute).
__global__ __launch_bounds__(64) void k_crf(const float* __restrict__ logits,
                                            const float* __restrict__ trans,
                                            float* __restrict__ totals) {
  int j = threadIdx.x;                 // tag index; active j < 25
  int b = blockIdx.x;
  bool act = j < T_;
  __shared__ __align__(16) float qS[32];
  float Ecol[T_];
#pragma unroll
  for (int i = 0; i < T_; i++)
    Ecol[i] = act ? __expf(trans[i * T_ + j]) : 0.f;
  if (j >= T_ && j < 32) qS[j] = 0.f;  // zero-pad q[25..31] once
  float tstop = act ? trans[j * T_ + STOP_] : 0.f;
  float prev = act ? 0.f : -INFINITY;
  const float* lg = logits + (size_t)b * S_ * T_;
  float ltn = act ? lg[j] : 0.f;
  asm volatile("s_waitcnt lgkmcnt(0)" ::: "memory");
  for (int t = 0; t < S_; t++) {
    float lt = ltn;
    if (t + 1 < S_) ltn = act ? lg[(size_t)(t + 1) * T_ + j] : 0.f;
    float m = __builtin_bit_cast(float,
        __builtin_amdgcn_readfirstlane(__builtin_bit_cast(int, prev)));
    float q = __expf(prev - m);
    if (act) qS[j] = q;
    asm volatile("s_waitcnt lgkmcnt(0)" ::: "memory");
    const float4* q4 = (const float4*)qS;
    float4 qv0 = q4[0], qv1 = q4[1], qv2 = q4[2], qv3 = q4[3];
    float4 qv4 = q4[4], qv5 = q4[5], qv6 = q4[6];
    float s0, s1, s2, s3;
    s0 = qv0.x * Ecol[0];  s1 = qv0.y * Ecol[1];
    s2 = qv0.z * Ecol[2];  s3 = qv0.w * Ecol[3];
    s0 += qv1.x * Ecol[4];  s1 += qv1.y * Ecol[5];
    s2 += qv1.z * Ecol[6];  s3 += qv1.w * Ecol[7];
    s0 += qv2.x * Ecol[8];  s1 += qv2.y * Ecol[9];
    s2 += qv2.z * Ecol[10]; s3 += qv2.w * Ecol[11];
    s0 += qv3.x * Ecol[12]; s1 += qv3.y * Ecol[13];
    s2 += qv3.z * Ecol[14]; s3 += qv3.w * Ecol[15];
    s0 += qv4.x * Ecol[16]; s1 += qv4.y * Ecol[17];
    s2 += qv4.z * Ecol[18]; s3 += qv4.w * Ecol[19];
    s0 += qv5.x * Ecol[20]; s1 += qv5.y * Ecol[21];
    s2 += qv5.z * Ecol[22]; s3 += qv5.w * Ecol[23];
    s0 += qv6.x * Ecol[24];
    float s = (s0 + s1) + (s2 + s3);
    prev = lt + m + __logf(s);         // s==0 -> -inf (matches fp32 underflow)
    if (!act) prev = -INFINITY;
  }
  float v = prev + tstop;              // j>=25: -inf
  float m = v;
#pragma unroll
  for (int off = 32; off > 0; off >>= 1)
    m = fmaxf(m, __shfl_xor(m, off, 64));
  float e = __expf(v - m);
#pragma unroll
  for (int off = 32; off > 0; off >>= 1)
    e += __shfl_xor(e, off, 64);
  if (j == 0) totals[b] = m + __logf(e);
}

// ---------------- K5: gold path score per b ----------------------------------
__global__ __launch_bounds__(256) void k_real(const float* __restrict__ logits,
                                              const int* __restrict__ tags,
                                              const float* __restrict__ trans,
                                              float* __restrict__ reals) {
  __shared__ float red[256];
  int b = blockIdx.x;
  float acc = 0.f;
  for (int s = threadIdx.x; s < S_; s += 256) {
    int tg = tags[(size_t)b * S_ + s];
    int pv = (s == 0) ? START_ : tags[(size_t)b * S_ + s - 1];
    acc += logits[((size_t)b * S_ + s) * T_ + tg] + trans[pv * T_ + tg];
  }
  red[threadIdx.x] = acc;
  __syncthreads();
  for (int off = 128; off > 0; off >>= 1) {
    if (threadIdx.x < off) red[threadIdx.x] += red[threadIdx.x + off];
    __syncthreads();
  }
  if (threadIdx.x == 0)
    reals[b] = red[0] + trans[tags[(size_t)b * S_ + S_ - 1] * T_ + STOP_];
}

// ---------------- K6: out = sum_b totals - reals -----------------------------
__global__ __launch_bounds__(256) void k_final(const float* __restrict__ totals,
                                               const float* __restrict__ reals,
                                               float* __restrict__ out) {
  __shared__ float red[256];
  float acc = 0.f;
  for (int b = threadIdx.x; b < B_; b += 256) acc += totals[b] - reals[b];
  red[threadIdx.x] = acc;
  __syncthreads();
  for (int off = 128; off > 0; off >>= 1) {
    if (threadIdx.x < off) red[threadIdx.x] += red[threadIdx.x + off];
    __syncthreads();
  }
  if (threadIdx.x == 0) out[0] = red[0];
}

// ws: Pf 5,120,000 | Pb 5,120,000 | feat(bf16) 67,108,864 | logits 26,214,400
//   | WoutP 8,192 | totals 2,048 | reals 2,048
extern "C" void kernel_launch(void* const* d_in, const int* in_sizes, int n_in,
                              void* d_out, int out_size, void* d_ws, size_t ws_size,
                              hipStream_t stream) {
  const int*   sentences = (const int*)d_in[0];
  const int*   tags  = (const int*)d_in[1];
  const float* embed = (const float*)d_in[2];
  const float* Wih_f = (const float*)d_in[3];
  const float* Whh_f = (const float*)d_in[4];
  const float* bih_f = (const float*)d_in[5];
  const float* bhh_f = (const float*)d_in[6];
  const float* Wih_b = (const float*)d_in[7];
  const float* Whh_b = (const float*)d_in[8];
  const float* bih_b = (const float*)d_in[9];
  const float* bhh_b = (const float*)d_in[10];
  const float* h0    = (const float*)d_in[11];
  const float* c0    = (const float*)d_in[12];
  const float* Wout  = (const float*)d_in[13];
  const float* bout  = (const float*)d_in[14];
  const float* trans = (const float*)d_in[15];

  char* ws = (char*)d_ws;
  float* Pf = (float*)(ws);
  float* Pb = (float*)(ws + 5120000);
  __hip_bfloat16* feat = (__hip_bfloat16*)(ws + 10240000);
  float* logits = (float*)(ws + 10240000 + 67108864);
  __hip_bfloat16* WoutP = (__hip_bfloat16*)(ws + 10240000 + 67108864 + 26214400);
  float* totals = (float*)(ws + 10240000 + 67108864 + 26214400 + 8192);
  float* reals  = totals + B_;
  float* out    = (float*)d_out;

  k_proj<<<dim3(313, 2), 256, 0, stream>>>(embed, Wih_f, Wih_b, Pf, Pb);
  k_prep<<<16, 256, 0, stream>>>(Wout, WoutP);
  k_lstm<<<1024, 64, 0, stream>>>(sentences, Pf, Pb, Whh_f, Whh_b,
                                  bih_f, bhh_f, bih_b, bhh_b, h0, c0, feat);
  k_logits<<<4096, 256, 0, stream>>>(feat, WoutP, bout, logits);
  k_crf<<<512, 64, 0, stream>>>(logits, trans, totals);
  k_real<<<512, 256, 0, stream>>>(logits, tags, trans, reals);
  k_final<<<1, 256, 0, stream>>>(totals, reals, out);
}